// Round 1
// baseline (1357.243 us; speedup 1.0000x reference)
//
#include <hip/hip_runtime.h>
#include <hip/hip_bf16.h>

// out[m, n] = sum_{e : rows[e]==m} vals[e] * A[cols[e], n]
// M = 100000, K = 100000, N = 64, NNZ = 1600000
//
// Round 0: correctness-first atomic scatter.
//  - 16 threads per nonzero; each thread handles a float4 (4 columns).
//  - A-row gather is 256 B/nnz, fully coalesced across the 16 lanes.
//  - atomicAdd f32 into out (device-scope by default on CDNA).

#define NCOLS 64

__global__ void spmm_scatter_atomic(const float* __restrict__ vals,
                                    const float* __restrict__ A,
                                    const int* __restrict__ rows,
                                    const int* __restrict__ cols,
                                    float* __restrict__ out,
                                    int nnz) {
    int t = blockIdx.x * blockDim.x + threadIdx.x;
    int e = t >> 4;        // nonzero index (16 threads per nnz)
    int q = t & 15;        // which float4 of the 64-wide row
    if (e >= nnz) return;

    float v = vals[e];
    int   r = rows[e];
    int   c = cols[e];

    const float4 a = *reinterpret_cast<const float4*>(A + (size_t)c * NCOLS + q * 4);
    float* o = out + (size_t)r * NCOLS + q * 4;

    atomicAdd(o + 0, v * a.x);
    atomicAdd(o + 1, v * a.y);
    atomicAdd(o + 2, v * a.z);
    atomicAdd(o + 3, v * a.w);
}

extern "C" void kernel_launch(void* const* d_in, const int* in_sizes, int n_in,
                              void* d_out, int out_size, void* d_ws, size_t ws_size,
                              hipStream_t stream) {
    const float* vals = (const float*)d_in[0];
    const float* A    = (const float*)d_in[1];
    const int*   rows = (const int*)d_in[2];
    const int*   cols = (const int*)d_in[3];
    float*       out  = (float*)d_out;

    const int nnz = in_sizes[0];

    // Harness poisons d_out with 0xAA and does NOT re-zero between replays.
    hipMemsetAsync(d_out, 0, (size_t)out_size * sizeof(float), stream);

    const int threads_total = nnz * 16;
    const int block = 256;
    const int grid  = (threads_total + block - 1) / block;
    spmm_scatter_atomic<<<grid, block, 0, stream>>>(vals, A, rows, cols, out, nnz);
}

// Round 2
// 476.204 us; speedup vs baseline: 2.8501x; 2.8501x over previous
//
#include <hip/hip_runtime.h>
#include <hip/hip_bf16.h>

// out[m, n] = sum_{e : rows[e]==m} vals[e] * A[cols[e], n]
// M = 100000 (derived: out_size/64), K = 100000, N = 64, NNZ = 1600000
//
// Round 2: CSR-build + atomic-free reduce.
//  Round-1 evidence: 1.6384 GB WRITE_SIZE = 102.4M f32 atomics x 16 B
//  write-through; kernel was atomic-bound (17% HBM, 1% VALU).
//  Plan: histogram(rows) -> scan -> scatter vals/cols row-sorted -> per-row
//  register reduce, output written exactly once, zero f32 atomics.

#define NCOLS 64

// ---- fallback (round-1 kernel) if ws is too small ----
__global__ void spmm_scatter_atomic(const float* __restrict__ vals,
                                    const float* __restrict__ A,
                                    const int* __restrict__ rows,
                                    const int* __restrict__ cols,
                                    float* __restrict__ out,
                                    int nnz) {
    int t = blockIdx.x * blockDim.x + threadIdx.x;
    int e = t >> 4;
    int q = t & 15;
    if (e >= nnz) return;
    float v = vals[e];
    int   r = rows[e];
    int   c = cols[e];
    const float4 a = *reinterpret_cast<const float4*>(A + (size_t)c * NCOLS + q * 4);
    float* o = out + (size_t)r * NCOLS + q * 4;
    atomicAdd(o + 0, v * a.x);
    atomicAdd(o + 1, v * a.y);
    atomicAdd(o + 2, v * a.z);
    atomicAdd(o + 3, v * a.w);
}

// ---- step 1: per-row nnz histogram (int atomics into 400 KB, L2-resident) ----
__global__ void hist_rows(const int* __restrict__ rows, int* __restrict__ cnt, int nnz) {
    int t = blockIdx.x * blockDim.x + threadIdx.x;
    int stride = gridDim.x * blockDim.x;
    for (int e = t; e < nnz; e += stride) {
        atomicAdd(&cnt[rows[e]], 1);
    }
}

// ---- step 2: single-block exclusive scan of cnt[M] ----
// In-place: cnt[] becomes the scatter cursor start (== row_ptr value),
// and row_ptr[] gets the same prefix, plus row_ptr[M] = nnz.
__global__ void scan_rows(int* __restrict__ cnt, int* __restrict__ row_ptr,
                          int M, int nnz) {
    __shared__ int lds[1024];
    const int t = threadIdx.x;           // blockDim.x == 1024, single block
    const int chunk = (M + 1023) / 1024;
    const int lo = t * chunk;
    const int hi = min(lo + chunk, M);

    int local = 0;
    for (int i = lo; i < hi; ++i) local += cnt[i];
    lds[t] = local;
    __syncthreads();

    // Hillis-Steele inclusive scan over 1024 thread sums
    for (int off = 1; off < 1024; off <<= 1) {
        int v = (t >= off) ? lds[t - off] : 0;
        __syncthreads();
        lds[t] += v;
        __syncthreads();
    }
    int run = lds[t] - local;            // exclusive prefix of this thread's chunk

    for (int i = lo; i < hi; ++i) {
        int c = cnt[i];
        cnt[i]     = run;                // scatter cursor
        row_ptr[i] = run;                // CSR pointer (stable copy)
        run += c;
    }
    if (t == 0) row_ptr[M] = nnz;
}

// ---- step 3: scatter vals/cols into row-sorted order ----
__global__ void scatter_csr(const float* __restrict__ vals,
                            const int* __restrict__ rows,
                            const int* __restrict__ cols,
                            int* __restrict__ cursor,
                            float* __restrict__ pvals,
                            int* __restrict__ pcols,
                            int nnz) {
    int t = blockIdx.x * blockDim.x + threadIdx.x;
    int stride = gridDim.x * blockDim.x;
    for (int e = t; e < nnz; e += stride) {
        int r = rows[e];
        int slot = atomicAdd(&cursor[r], 1);
        pvals[slot] = vals[e];
        pcols[slot] = cols[e];
    }
}

// ---- step 4: per-row reduce, 16 lanes per row, zero atomics ----
__global__ void spmm_reduce(const float* __restrict__ pvals,
                            const int* __restrict__ pcols,
                            const int* __restrict__ row_ptr,
                            const float* __restrict__ A,
                            float* __restrict__ out,
                            int M) {
    int t = blockIdx.x * blockDim.x + threadIdx.x;
    int m = t >> 4;        // row
    int q = t & 15;        // which float4 of the 64-wide row
    if (m >= M) return;

    int e0 = row_ptr[m];
    int e1 = row_ptr[m + 1];

    float4 acc = make_float4(0.f, 0.f, 0.f, 0.f);
    for (int e = e0; e < e1; ++e) {
        float v = pvals[e];
        int   c = pcols[e];
        const float4 a = *reinterpret_cast<const float4*>(A + (size_t)c * NCOLS + q * 4);
        acc.x += v * a.x;
        acc.y += v * a.y;
        acc.z += v * a.z;
        acc.w += v * a.w;
    }
    // write exactly once (also initializes empty rows to zero over poison)
    *reinterpret_cast<float4*>(out + (size_t)m * NCOLS + q * 4) = acc;
}

extern "C" void kernel_launch(void* const* d_in, const int* in_sizes, int n_in,
                              void* d_out, int out_size, void* d_ws, size_t ws_size,
                              hipStream_t stream) {
    const float* vals = (const float*)d_in[0];
    const float* A    = (const float*)d_in[1];
    const int*   rows = (const int*)d_in[2];
    const int*   cols = (const int*)d_in[3];
    float*       out  = (float*)d_out;

    const int nnz = in_sizes[0];
    const int M   = out_size / NCOLS;

    // workspace layout (bytes)
    size_t off_cursor = 0;                                   // M ints (cnt -> cursor)
    size_t off_rowptr = (off_cursor + (size_t)M * 4 + 15) & ~(size_t)15;  // M+1 ints
    size_t off_pvals  = (off_rowptr + ((size_t)M + 1) * 4 + 15) & ~(size_t)15; // nnz f32
    size_t off_pcols  = (off_pvals + (size_t)nnz * 4 + 15) & ~(size_t)15;      // nnz i32
    size_t need       = off_pcols + (size_t)nnz * 4;

    if (need > ws_size) {
        // fallback: round-1 atomic scatter (correct, slower)
        hipMemsetAsync(d_out, 0, (size_t)out_size * sizeof(float), stream);
        int threads_total = nnz * 16;
        int block = 256;
        int grid = (threads_total + block - 1) / block;
        spmm_scatter_atomic<<<grid, block, 0, stream>>>(vals, A, rows, cols, out, nnz);
        return;
    }

    char* ws = (char*)d_ws;
    int*   cursor  = (int*)(ws + off_cursor);
    int*   row_ptr = (int*)(ws + off_rowptr);
    float* pvals   = (float*)(ws + off_pvals);
    int*   pcols   = (int*)(ws + off_pcols);

    // zero the histogram counters
    hipMemsetAsync(cursor, 0, (size_t)M * 4, stream);

    // 1. histogram
    {
        int block = 256;
        int grid = min((nnz + block - 1) / block, 2048);
        hist_rows<<<grid, block, 0, stream>>>(rows, cursor, nnz);
    }
    // 2. scan (single block of 1024)
    scan_rows<<<1, 1024, 0, stream>>>(cursor, row_ptr, M, nnz);
    // 3. scatter into row-sorted order
    {
        int block = 256;
        int grid = min((nnz + block - 1) / block, 2048);
        scatter_csr<<<grid, block, 0, stream>>>(vals, rows, cols, cursor, pvals, pcols, nnz);
    }
    // 4. reduce (16 lanes per row, no atomics, writes out exactly once)
    {
        int threads_total = M * 16;
        int block = 256;
        int grid = (threads_total + block - 1) / block;
        spmm_reduce<<<grid, block, 0, stream>>>(pvals, pcols, row_ptr, A, out, M);
    }
}

// Round 3
// 271.798 us; speedup vs baseline: 4.9936x; 1.7521x over previous
//
#include <hip/hip_runtime.h>
#include <hip/hip_bf16.h>

// out[m, n] = sum_{e : rows[e]==m} vals[e] * A[cols[e], n]
// M = 100000, K = 100000, N = 64, NNZ = 1600000
//
// Round 3: fix the scan (R2's single-block scan_rows was 230 us = half the
// total, latency-bound on one CU). Hierarchical 3-kernel scan + packed
// (val,col) int2 CSR to halve scattered writes.

#define NCOLS   64
#define SCAN_NB 256   // blocks in hierarchical scan
#define SCAN_BT 256   // threads per scan block

// ---- fallback (round-1 kernel) if ws is too small ----
__global__ void spmm_scatter_atomic(const float* __restrict__ vals,
                                    const float* __restrict__ A,
                                    const int* __restrict__ rows,
                                    const int* __restrict__ cols,
                                    float* __restrict__ out,
                                    int nnz) {
    int t = blockIdx.x * blockDim.x + threadIdx.x;
    int e = t >> 4;
    int q = t & 15;
    if (e >= nnz) return;
    float v = vals[e];
    int   r = rows[e];
    int   c = cols[e];
    const float4 a = *reinterpret_cast<const float4*>(A + (size_t)c * NCOLS + q * 4);
    float* o = out + (size_t)r * NCOLS + q * 4;
    atomicAdd(o + 0, v * a.x);
    atomicAdd(o + 1, v * a.y);
    atomicAdd(o + 2, v * a.z);
    atomicAdd(o + 3, v * a.w);
}

// ---- step 1: per-row nnz histogram (int atomics, L2-resident) ----
__global__ void hist_rows(const int* __restrict__ rows, int* __restrict__ cnt, int nnz) {
    int t = blockIdx.x * blockDim.x + threadIdx.x;
    int stride = gridDim.x * blockDim.x;
    for (int e = t; e < nnz; e += stride) {
        atomicAdd(&cnt[rows[e]], 1);
    }
}

// ---- step 2a: per-block partial sums of cnt ----
__global__ void scan_partial(const int* __restrict__ cnt, int* __restrict__ bsum, int M) {
    __shared__ int lds[SCAN_BT];
    int b = blockIdx.x, t = threadIdx.x;
    int cpb = (M + gridDim.x - 1) / gridDim.x;
    int lo = b * cpb, hi = min(lo + cpb, M);
    int s = 0;
    for (int i = lo + t; i < hi; i += SCAN_BT) s += cnt[i];
    lds[t] = s;
    __syncthreads();
    for (int off = SCAN_BT / 2; off > 0; off >>= 1) {
        if (t < off) lds[t] += lds[t + off];
        __syncthreads();
    }
    if (t == 0) bsum[b] = lds[0];
}

// ---- step 2b: exclusive scan of SCAN_NB block sums (1 block) ----
__global__ void scan_bsums(int* __restrict__ bsum, int nb) {
    __shared__ int lds[SCAN_NB];
    int t = threadIdx.x;
    int v = (t < nb) ? bsum[t] : 0;
    lds[t] = v;
    __syncthreads();
    for (int off = 1; off < SCAN_NB; off <<= 1) {
        int u = (t >= off) ? lds[t - off] : 0;
        __syncthreads();
        lds[t] += u;
        __syncthreads();
    }
    if (t < nb) bsum[t] = lds[t] - v;   // exclusive prefix
}

// ---- step 2c: write per-element exclusive prefix -> cursor + row_ptr ----
__global__ void scan_write(int* __restrict__ cnt, int* __restrict__ row_ptr,
                           const int* __restrict__ bsum, int M, int nnz) {
    __shared__ int lds[SCAN_BT];
    int b = blockIdx.x, t = threadIdx.x;
    int cpb = (M + gridDim.x - 1) / gridDim.x;
    int spt = (cpb + SCAN_BT - 1) / SCAN_BT;
    int base = b * cpb;
    int lim = min(base + cpb, M);
    int lo = base + t * spt;
    int hi = min(lo + spt, lim);
    int s = 0;
    for (int i = lo; i < hi; ++i) s += cnt[i];
    lds[t] = s;
    __syncthreads();
    for (int off = 1; off < SCAN_BT; off <<= 1) {
        int u = (t >= off) ? lds[t - off] : 0;
        __syncthreads();
        lds[t] += u;
        __syncthreads();
    }
    int run = bsum[b] + lds[t] - s;     // exclusive prefix for this thread's span
    for (int i = lo; i < hi; ++i) {
        int c = cnt[i];
        cnt[i]     = run;               // scatter cursor
        row_ptr[i] = run;               // CSR pointer
        run += c;
    }
    if (b == 0 && t == 0) row_ptr[M] = nnz;
}

// ---- step 3: scatter packed (val,col) into row-sorted order ----
__global__ void scatter_csr(const float* __restrict__ vals,
                            const int* __restrict__ rows,
                            const int* __restrict__ cols,
                            int* __restrict__ cursor,
                            int2* __restrict__ pvc,
                            int nnz) {
    int t = blockIdx.x * blockDim.x + threadIdx.x;
    int stride = gridDim.x * blockDim.x;
    for (int e = t; e < nnz; e += stride) {
        int r = rows[e];
        int slot = atomicAdd(&cursor[r], 1);
        pvc[slot] = make_int2(__float_as_int(vals[e]), cols[e]);
    }
}

// ---- step 4: per-row reduce, 16 lanes per row, zero atomics ----
__global__ void spmm_reduce(const int2* __restrict__ pvc,
                            const int* __restrict__ row_ptr,
                            const float* __restrict__ A,
                            float* __restrict__ out,
                            int M) {
    int t = blockIdx.x * blockDim.x + threadIdx.x;
    int m = t >> 4;        // row
    int q = t & 15;        // which float4 of the 64-wide row
    if (m >= M) return;

    int e0 = row_ptr[m];
    int e1 = row_ptr[m + 1];

    float4 acc = make_float4(0.f, 0.f, 0.f, 0.f);
    for (int e = e0; e < e1; ++e) {
        int2 vc = pvc[e];
        float v = __int_as_float(vc.x);
        const float4 a = *reinterpret_cast<const float4*>(A + (size_t)vc.y * NCOLS + q * 4);
        acc.x += v * a.x;
        acc.y += v * a.y;
        acc.z += v * a.z;
        acc.w += v * a.w;
    }
    *reinterpret_cast<float4*>(out + (size_t)m * NCOLS + q * 4) = acc;
}

extern "C" void kernel_launch(void* const* d_in, const int* in_sizes, int n_in,
                              void* d_out, int out_size, void* d_ws, size_t ws_size,
                              hipStream_t stream) {
    const float* vals = (const float*)d_in[0];
    const float* A    = (const float*)d_in[1];
    const int*   rows = (const int*)d_in[2];
    const int*   cols = (const int*)d_in[3];
    float*       out  = (float*)d_out;

    const int nnz = in_sizes[0];
    const int M   = out_size / NCOLS;

    // workspace layout (bytes)
    size_t off_cursor = 0;                                                     // M ints
    size_t off_rowptr = (off_cursor + (size_t)M * 4 + 15) & ~(size_t)15;       // M+1 ints
    size_t off_bsum   = (off_rowptr + ((size_t)M + 1) * 4 + 15) & ~(size_t)15; // SCAN_NB ints
    size_t off_pvc    = (off_bsum + (size_t)SCAN_NB * 4 + 15) & ~(size_t)15;   // nnz int2
    size_t need       = off_pvc + (size_t)nnz * 8;

    if (need > ws_size) {
        hipMemsetAsync(d_out, 0, (size_t)out_size * sizeof(float), stream);
        int threads_total = nnz * 16;
        int block = 256;
        int grid = (threads_total + block - 1) / block;
        spmm_scatter_atomic<<<grid, block, 0, stream>>>(vals, A, rows, cols, out, nnz);
        return;
    }

    char* ws = (char*)d_ws;
    int*  cursor  = (int*)(ws + off_cursor);
    int*  row_ptr = (int*)(ws + off_rowptr);
    int*  bsum    = (int*)(ws + off_bsum);
    int2* pvc     = (int2*)(ws + off_pvc);

    hipMemsetAsync(cursor, 0, (size_t)M * 4, stream);

    // 1. histogram
    {
        int block = 256;
        int grid = min((nnz + block - 1) / block, 2048);
        hist_rows<<<grid, block, 0, stream>>>(rows, cursor, nnz);
    }
    // 2. hierarchical exclusive scan: cnt -> cursor/row_ptr
    scan_partial<<<SCAN_NB, SCAN_BT, 0, stream>>>(cursor, bsum, M);
    scan_bsums<<<1, SCAN_NB, 0, stream>>>(bsum, SCAN_NB);
    scan_write<<<SCAN_NB, SCAN_BT, 0, stream>>>(cursor, row_ptr, bsum, M, nnz);
    // 3. scatter packed (val,col) row-sorted
    {
        int block = 256;
        int grid = min((nnz + block - 1) / block, 2048);
        scatter_csr<<<grid, block, 0, stream>>>(vals, rows, cols, cursor, pvc, nnz);
    }
    // 4. reduce (16 lanes per row, no atomics, single output write)
    {
        int threads_total = M * 16;
        int block = 256;
        int grid = (threads_total + block - 1) / block;
        spmm_reduce<<<grid, block, 0, stream>>>(pvc, row_ptr, A, out, M);
    }
}